// Round 10
// baseline (95.713 us; speedup 1.0000x reference)
//
#include <hip/hip_runtime.h>

#define N_NODES 10000
#define N_EDGES 640000
#define D 128
#define MAXDEG 128
#define NBUCK 157            // ceil(10000 / 64) buckets of 64 dst nodes
#define BCAP 6144            // bucket capacity; mean 4076 -> huge margin
#define EPT 5                // edges/thread in pass1: 500 blocks * 256 * 5 = 640000
#define ZROW 10000           // zero-row index used for adj padding

typedef unsigned int uint;
typedef unsigned short u16;
typedef short bf16x8 __attribute__((ext_vector_type(8)));
typedef float f32x4 __attribute__((ext_vector_type(4)));

__device__ __forceinline__ u16 f2bf(float f) {
    uint u = __float_as_uint(f);
    return (u16)((u + 0x7fffu + ((u >> 16) & 1u)) >> 16);   // round-nearest-even
}
__device__ __forceinline__ float bflo(uint v) { return __uint_as_float(v << 16); }
__device__ __forceinline__ float bfhi(uint v) { return __uint_as_float(v & 0xffff0000u); }

__device__ __forceinline__ int edge_at(const void* ei, int is32, int idx) {
    if (is32) return ((const int*)ei)[idx];
    return (int)((const long long*)ei)[idx];
}

// ---------------------------------------------------------------------------
// Pass 1: bin packed (dst<<16 | src) edges into NBUCK global bucket arrays.
// Per-block dtype probe: int64 layout -> odd 32b words (high halves) all 0.
__global__ __launch_bounds__(256)
void binp1_kernel(const void* __restrict__ ei, int* __restrict__ gcount,
                  uint* __restrict__ gbucket) {
    __shared__ int hist[NBUCK];
    __shared__ int base[NBUCK];
    __shared__ int s_is32;
    const int t = threadIdx.x;
    if (t < NBUCK) hist[t] = 0;
    if (t == 0) s_is32 = 0;
    __syncthreads();
    const int e0 = blockIdx.x * (256 * EPT);
    if (((const int*)ei)[2 * (e0 + t) + 1] != 0) s_is32 = 1;   // benign race
    __syncthreads();
    const int is32 = s_is32;
    uint pk[EPT];
    int  rk[EPT];
#pragma unroll
    for (int i = 0; i < EPT; ++i) {
        int e  = e0 + i * 256 + t;
        int s  = edge_at(ei, is32, e);
        int dn = edge_at(ei, is32, N_EDGES + e);
        pk[i] = ((uint)dn << 16) | (uint)s;
        rk[i] = atomicAdd(&hist[dn >> 6], 1);
    }
    __syncthreads();
    if (t < NBUCK) base[t] = atomicAdd(&gcount[t], hist[t]);
    __syncthreads();
#pragma unroll
    for (int i = 0; i < EPT; ++i) {
        int bkt = (int)(pk[i] >> 22);
        int pos = base[bkt] + rk[i];
        if (pos < BCAP) gbucket[(size_t)bkt * BCAP + pos] = pk[i];
    }
}

// ---------------------------------------------------------------------------
// Fused prep: blocks [0,157) counting-sort buckets -> padded adj (pad=ZROW);
// [157,782) cast x -> packed bf16; [782,1038) build WT; 1038 zeroes xb2 ZROW.
__global__ __launch_bounds__(256)
void prep_kernel(const int* __restrict__ gcount, const uint* __restrict__ gbucket,
                 u16* __restrict__ adj, int* __restrict__ deg_g,
                 const float* __restrict__ x, uint* __restrict__ xb2,
                 const float* __restrict__ Wl0, const float* __restrict__ Wr0,
                 const float* __restrict__ Wl1, const float* __restrict__ Wr1,
                 u16* __restrict__ WT0, u16* __restrict__ WT1) {
    const int b = blockIdx.x;
    const int t = threadIdx.x;
    __shared__ __align__(16) u16 tile[64][MAXDEG];   // 16 KB
    __shared__ int cur[64];
    if (b < NBUCK) {
        uint* tw = (uint*)&tile[0][0];               // pad pattern = ZROW|ZROW
#pragma unroll
        for (int q = 0; q < 16; ++q) tw[t + q * 256] = ((uint)ZROW << 16) | ZROW;
        if (t < 64) cur[t] = 0;
        __syncthreads();
        const int total = min(gcount[b], BCAP);
        for (int e = t; e < total; e += 256) {
            uint pk = gbucket[(size_t)b * BCAP + e];
            int ln = (int)((pk >> 16) & 63u);
            int r = atomicAdd(&cur[ln], 1);
            if (r < MAXDEG) tile[ln][r] = (u16)(pk & 0xffffu);
        }
        __syncthreads();
        const int node0 = b * 64;
        if (t < 64 && node0 + t < N_NODES) deg_g[node0 + t] = cur[t];
        const uint4* ts = (const uint4*)&tile[0][0];
#pragma unroll
        for (int q = 0; q < 4; ++q) {
            int i = t + q * 256;
            int node = node0 + (i >> 4);
            if (node < N_NODES) ((uint4*)(adj + (size_t)node * MAXDEG))[i & 15] = ts[i];
        }
    } else if (b < NBUCK + 625) {
        int idx = (b - NBUCK) * 256 + t;             // 0..159999, exact
        const float4* p = (const float4*)x + (size_t)idx * 2;
        float4 a = p[0], bb = p[1];
        uint4 r;
        r.x = (uint)f2bf(a.x) | ((uint)f2bf(a.y) << 16);
        r.y = (uint)f2bf(a.z) | ((uint)f2bf(a.w) << 16);
        r.z = (uint)f2bf(bb.x) | ((uint)f2bf(bb.y) << 16);
        r.w = (uint)f2bf(bb.z) | ((uint)f2bf(bb.w) << 16);
        ((uint4*)xb2)[idx] = r;
    } else if (b < NBUCK + 625 + 256) {
        int b2 = b - (NBUCK + 625);
        int layer = b2 >> 7, d = b2 & 127, k = t;
        const float* Wl = layer ? Wl1 : Wl0;
        const float* Wr = layer ? Wr1 : Wr0;
        u16* WT = layer ? WT1 : WT0;
        float v = (k < 128) ? Wl[k * D + d] : Wr[(k - 128) * D + d];
        WT[(size_t)d * 256 + k] = f2bf(v);
    } else {
        if (t < 16) ((uint4*)(xb2 + (size_t)ZROW * 64))[t] = make_uint4(0, 0, 0, 0);
    }
}

// ---------------------------------------------------------------------------
// Fused layer: 4 nodes/block, 256 thr, grid 2500 (full gather parallelism).
// Gather: wave w -> node nb+w, v2 structure (lane (g,c): 4 edges x uint4,
// 1 KB/wave-instr); mean -> bf16 -> LDS A row w (XOR-swizzle ^ (row<<4)).
// Gemm: wave w -> cols [w*32,w*32+32); A-frag rows 4..15 are zero (M=4 tile);
// A/B share k-map k = kk*32 + q*8 + j so internal k-permutation cancels.
// C/D: col = lane&15, row = (lane>>4)*4 + reg  [HW-verified] -> rows 0..3
// live in q==0 lanes only.
__global__ __launch_bounds__(256)
void fused_layer_kernel(const uint* __restrict__ src2, const u16* __restrict__ adj,
                        const int* __restrict__ deg_g, const u16* __restrict__ WT,
                        const float* __restrict__ bias,
                        float* __restrict__ outf /* may be null */,
                        u16* __restrict__ outb /* may be null */) {
    __shared__ __align__(16) u16 A_lds[4][256];      // 2 KB
    const int t = threadIdx.x;
    const int w = t >> 6, l = t & 63;
    const int nb = blockIdx.x * 4;
    const int node = nb + w;

    // ---- gather phase ----
    const int g = l >> 4, c = l & 15;
    const int half = g >> 1, sh = (g & 1) << 4;
    const int dg = deg_g[node];
    const int cnt = min(dg, MAXDEG);
    const uint4* __restrict__ rowq = (const uint4*)(adj + (size_t)node * MAXDEG);
    float acc[8];
#pragma unroll
    for (int i = 0; i < 8; ++i) acc[i] = 0.f;
    const int nch = (cnt + 15) >> 4;
#pragma unroll 2
    for (int ch = 0; ch < nch; ++ch) {
        uint4 wa = rowq[2 * ch];
        uint4 wb = rowq[2 * ch + 1];
        uint a0 = half ? wa.y : wa.x;
        uint a1 = half ? wa.w : wa.z;
        uint b0 = half ? wb.y : wb.x;
        uint b1 = half ? wb.w : wb.z;
        uint id0 = (a0 >> sh) & 0xffffu;
        uint id1 = (a1 >> sh) & 0xffffu;
        uint id2 = (b0 >> sh) & 0xffffu;
        uint id3 = (b1 >> sh) & 0xffffu;
        uint4 v0 = ((const uint4*)(src2 + (size_t)id0 * 64))[c];
        uint4 v1 = ((const uint4*)(src2 + (size_t)id1 * 64))[c];
        uint4 v2 = ((const uint4*)(src2 + (size_t)id2 * 64))[c];
        uint4 v3 = ((const uint4*)(src2 + (size_t)id3 * 64))[c];
        acc[0] += bflo(v0.x) + bflo(v1.x) + bflo(v2.x) + bflo(v3.x);
        acc[1] += bfhi(v0.x) + bfhi(v1.x) + bfhi(v2.x) + bfhi(v3.x);
        acc[2] += bflo(v0.y) + bflo(v1.y) + bflo(v2.y) + bflo(v3.y);
        acc[3] += bfhi(v0.y) + bfhi(v1.y) + bfhi(v2.y) + bfhi(v3.y);
        acc[4] += bflo(v0.z) + bflo(v1.z) + bflo(v2.z) + bflo(v3.z);
        acc[5] += bfhi(v0.z) + bfhi(v1.z) + bfhi(v2.z) + bfhi(v3.z);
        acc[6] += bflo(v0.w) + bflo(v1.w) + bflo(v2.w) + bflo(v3.w);
        acc[7] += bfhi(v0.w) + bfhi(v1.w) + bfhi(v2.w) + bfhi(v3.w);
    }
#pragma unroll
    for (int i = 0; i < 8; ++i) {
        float r = acc[i];
        r += __shfl_xor(r, 16, 64);
        r += __shfl_xor(r, 32, 64);
        acc[i] = r;
    }
    char* arow = (char*)&A_lds[w][0];
    const int swz = w << 4;
    if (g == 0) {                                    // lanes 0..15: agg (k 0..127)
        float inv = 1.0f / fmaxf((float)dg, 1.0f);
        uint4 o;
        o.x = (uint)f2bf(acc[0] * inv) | ((uint)f2bf(acc[1] * inv) << 16);
        o.y = (uint)f2bf(acc[2] * inv) | ((uint)f2bf(acc[3] * inv) << 16);
        o.z = (uint)f2bf(acc[4] * inv) | ((uint)f2bf(acc[5] * inv) << 16);
        o.w = (uint)f2bf(acc[6] * inv) | ((uint)f2bf(acc[7] * inv) << 16);
        *(uint4*)(arow + ((c * 16) ^ swz)) = o;
    }
    if (l < 16) {                                    // x/h row (k 128..255)
        uint4 vx = ((const uint4*)(src2 + (size_t)node * 64))[l];
        *(uint4*)(arow + ((256 + l * 16) ^ swz)) = vx;
    }
    __syncthreads();

    // ---- gemm phase ----
    const int lr = l & 15, q = l >> 4;
    f32x4 acc0 = {0.f, 0.f, 0.f, 0.f}, acc1 = {0.f, 0.f, 0.f, 0.f};
    const u16* wt0 = WT + (size_t)(w * 32 + lr) * 256;
    const u16* wt1 = WT + (size_t)(w * 32 + 16 + lr) * 256;
    const char* abase = (const char*)&A_lds[lr & 3][0];
    const int aswz = (lr & 3) << 4;
#pragma unroll
    for (int kk = 0; kk < 8; ++kk) {
        bf16x8 af = {0, 0, 0, 0, 0, 0, 0, 0};
        if (lr < 4) af = *(const bf16x8*)(abase + ((kk * 64 + q * 16) ^ aswz));
        bf16x8 bf0 = *(const bf16x8*)(wt0 + kk * 32 + q * 8);
        bf16x8 bf1 = *(const bf16x8*)(wt1 + kk * 32 + q * 8);
        acc0 = __builtin_amdgcn_mfma_f32_16x16x32_bf16(af, bf0, acc0, 0, 0, 0);
        acc1 = __builtin_amdgcn_mfma_f32_16x16x32_bf16(af, bf1, acc1, 0, 0, 0);
    }
    if (q == 0) {                                    // C rows 0..3
        const int col0 = w * 32 + lr, col1 = col0 + 16;
        const float b0v = bias[col0], b1v = bias[col1];
#pragma unroll
        for (int j = 0; j < 4; ++j) {
            const int nd = nb + j;
            float v0 = acc0[j] + b0v; v0 = v0 > 0.f ? v0 : expm1f(v0);   // ELU
            float v1 = acc1[j] + b1v; v1 = v1 > 0.f ? v1 : expm1f(v1);
            if (outf) {
                outf[(size_t)nd * D + col0] = v0;
                outf[(size_t)nd * D + col1] = v1;
            }
            if (outb) {
                outb[(size_t)nd * D + col0] = f2bf(v0);
                outb[(size_t)nd * D + col1] = f2bf(v1);
            }
        }
    }
    // layer 0 zeroes the next layer's gather zero-row
    if (outb && blockIdx.x == 0 && t < 16)
        ((uint4*)(outb + (size_t)ZROW * D))[t] = make_uint4(0, 0, 0, 0);
}

// ---------------------------------------------------------------------------
extern "C" void kernel_launch(void* const* d_in, const int* in_sizes, int n_in,
                              void* d_out, int out_size, void* d_ws, size_t ws_size,
                              hipStream_t stream) {
    const float* x   = (const float*)d_in[0];
    const void*  ei  = d_in[1];
    const float* Wl0 = (const float*)d_in[2];
    const float* b0  = (const float*)d_in[3];
    const float* Wr0 = (const float*)d_in[4];
    const float* Wl1 = (const float*)d_in[5];
    const float* b1  = (const float*)d_in[6];
    const float* Wr1 = (const float*)d_in[7];
    float* out = (float*)d_out;

    char* ws = (char*)d_ws;
    // ws_size ~268 MB (per harness poison fills) -> no overlays needed.
    int*  gcount  = (int*)(ws + 1024);           // 628 B
    int*  deg     = (int*)(ws + 4096);           // 40 KB
    u16*  adj     = (u16*)(ws + 65536);          // 2.56 MB  -> 2,625,536
    uint* gbucket = (uint*)(ws + 3145728);       // 3.86 MB  -> 7,004,160
    uint* xb2     = (uint*)(ws + 7340032);       // 2.56 MB + zrow -> 9,900,288
    uint* yb2     = (uint*)(ws + 10485760);      // 2.56 MB + zrow -> 13,046,016
    u16*  WT0     = (u16*)(ws + 13631488);       // 64 KB
    u16*  WT1     = (u16*)(ws + 13697024);       // 64 KB -> ends 13,762,560

    hipMemsetAsync(ws, 0, 4096, stream);         // gcount

    binp1_kernel<<<500, 256, 0, stream>>>(ei, gcount, gbucket);
    prep_kernel<<<NBUCK + 625 + 256 + 1, 256, 0, stream>>>(
        gcount, gbucket, adj, deg, x, xb2, Wl0, Wr0, Wl1, Wr1, WT0, WT1);

    // layer 0: gather from xb2, gemm -> bf16 activations in yb2 (+ zrow)
    fused_layer_kernel<<<2500, 256, 0, stream>>>(xb2, adj, deg, WT0, b0,
                                                 (float*)0, (u16*)yb2);
    // layer 1: gather from yb2, gemm -> f32 final output
    fused_layer_kernel<<<2500, 256, 0, stream>>>(yb2, adj, deg, WT1, b1,
                                                 out, (u16*)0);
}